// Round 1
// baseline (723.245 us; speedup 1.0000x reference)
//
#include <hip/hip_runtime.h>
#include <math.h>
#include <stdint.h>

#define E_EDGES 131072
#define NN 32768      // NUM_NODES
#define DMEM 256
#define DEDGE 128
#define TDIM 64
#define HID 512
#define MSGD 256
#define INDIM 704     // 2*256+128+64

typedef __bf16 bf16_t;
typedef bf16_t bf16x8 __attribute__((ext_vector_type(8)));
typedef float f32x4 __attribute__((ext_vector_type(4)));

__device__ __forceinline__ unsigned short f2bf(float f) {
  unsigned int u = __float_as_uint(f);
  u += 0x7FFF + ((u >> 16) & 1);   // round-to-nearest-even
  return (unsigned short)(u >> 16);
}

__device__ __forceinline__ void gl_lds16(const bf16_t* g, bf16_t* l) {
  __builtin_amdgcn_global_load_lds(
      (__attribute__((address_space(1))) void*)(g),
      (__attribute__((address_space(3))) void*)(l), 16, 0, 0);
}

__global__ void cvt_bf16(const float* __restrict__ in, unsigned short* __restrict__ out, int n) {
  int i = blockIdx.x * 256 + threadIdx.x;
  if (i < n) out[i] = f2bf(in[i]);
}

// ---------------- fused GEMM1+GEMM2 ----------------
// Phase 1: h[128][512] = relu([src|dst|edge|cos(rel*tw+tb)] @ w1^T + b1)
//          (M-block of 128 edges, full N=512, K=704; A packed on the fly)
// h kept in LDS (padded [128][520] bf16, stride 1040B -> 2-way bank = free).
// Phase 2: msg[128][256] = h @ w2^T + b2, A-fragments read from LDS,
//          atomicAdd-scattered into sums[dst[row]*256 + col].
__global__ __launch_bounds__(512) void gemm12_fused(
    const float* __restrict__ src, const float* __restrict__ dmem,
    const float* __restrict__ edge, const float* __restrict__ rel,
    const float* __restrict__ tw, const float* __restrict__ tb,
    const bf16_t* __restrict__ w1b, const float* __restrict__ b1,
    const bf16_t* __restrict__ w2b, const float* __restrict__ b2,
    const int* __restrict__ dstid, float* __restrict__ sums) {
  // 149,504 B union:
  //   phase 1:  sA [128][32] @0 (8KB),  sB [512][32] @8KB (32KB)
  //   phase 1.5/2: hL [128][520] @0 (130KB), sB2 [256][32] @130KB (16KB)
  __shared__ alignas(16) bf16_t smem[74752];
  __shared__ float sTW[64], sTB[64], sRel[128];
  bf16_t* sA  = smem;                 // [128][32]
  bf16_t* sB  = smem + 128 * 32;      // [512][32]
  bf16_t* hL  = smem;                 // [128][520]
  bf16_t* sB2 = smem + 128 * 520;     // [256][32]

  const int bm = blockIdx.x;          // 1024 blocks, A read exactly once
  const int t = threadIdx.x;
  const int lane = t & 63;
  const int wave = t >> 6;
  const int wm  = (wave >> 2) * 64;   // 0 / 64
  const int wn1 = (wave & 3) * 128;   // phase-1 wave col (tile 64x128)
  const int wn2 = (wave & 3) * 64;    // phase-2 wave col (tile 64x64)

  if (t < 64) { sTW[t] = tw[t]; sTB[t] = tb[t]; }
  if (t >= 128 && t < 256) sRel[t - 128] = rel[(size_t)bm * 128 + (t - 128)];

  f32x4 acc[4][8];
#pragma unroll
  for (int i = 0; i < 4; i++)
#pragma unroll
    for (int j = 0; j < 8; j++) acc[i][j] = (f32x4){0.f, 0.f, 0.f, 0.f};

  // A staging: thread -> (row ar, col-group ac of 8)
  const int ar = t >> 2;           // 0..127
  const int ac = (t & 3) * 8;      // 0,8,16,24
  const size_t arow = (size_t)bm * 128 + ar;
  // B staging: rows 0..511 in 4 gl_lds16 waves-of-128-rows
  const bf16_t* gB = w1b + (size_t)(t >> 2) * 704 + (t & 3) * 8;
  bf16_t* lB = sB + (size_t)t * 8;

  const int lrow = lane & 15;
  const int kq = (lane >> 4) * 8;

  for (int k0 = 0; k0 < INDIM; k0 += 32) {
    gl_lds16(gB,                     lB);
    gl_lds16(gB + (size_t)128 * 704, lB + 128 * 32);
    gl_lds16(gB + (size_t)256 * 704, lB + 256 * 32);
    gl_lds16(gB + (size_t)384 * 704, lB + 384 * 32);
    gB += 32;

    bf16x8 av;
    if (k0 < 640) {
      const float* p;
      if (k0 < 256)      p = src  + arow * 256 + k0 + ac;
      else if (k0 < 512) p = dmem + arow * 256 + (k0 - 256) + ac;
      else               p = edge + arow * 128 + (k0 - 512) + ac;
      f32x4 u = *(const f32x4*)p;
      f32x4 v = *(const f32x4*)(p + 4);
      av[0] = (bf16_t)u[0]; av[1] = (bf16_t)u[1]; av[2] = (bf16_t)u[2]; av[3] = (bf16_t)u[3];
      av[4] = (bf16_t)v[0]; av[5] = (bf16_t)v[1]; av[6] = (bf16_t)v[2]; av[7] = (bf16_t)v[3];
    } else {
      float rv = sRel[ar];
      int kk = (k0 - 640) + ac;
#pragma unroll
      for (int j = 0; j < 8; j++)
        av[j] = (bf16_t)cosf(rv * sTW[kk + j] + sTB[kk + j]);
    }
    *(bf16x8*)(sA + ar * 32 + ac) = av;

    __syncthreads();
    bf16x8 af[4], bfr[8];
#pragma unroll
    for (int i = 0; i < 4; i++) af[i] = *(const bf16x8*)(sA + (wm + i * 16 + lrow) * 32 + kq);
#pragma unroll
    for (int i = 0; i < 8; i++) bfr[i] = *(const bf16x8*)(sB + (wn1 + i * 16 + lrow) * 32 + kq);
#pragma unroll
    for (int mi = 0; mi < 4; mi++)
#pragma unroll
      for (int ni = 0; ni < 8; ni++)
        acc[mi][ni] = __builtin_amdgcn_mfma_f32_16x16x32_bf16(af[mi], bfr[ni], acc[mi][ni], 0, 0, 0);
    __syncthreads();
  }

  // ---- phase 1.5: relu+bias, h -> LDS (bf16, padded stride 520) ----
  const int crow = (lane >> 4) * 4;
  const int ccol = lane & 15;
#pragma unroll
  for (int ni = 0; ni < 8; ni++) {
    int col = wn1 + ni * 16 + ccol;
    float bv = b1[col];
#pragma unroll
    for (int mi = 0; mi < 4; mi++) {
#pragma unroll
      for (int r = 0; r < 4; r++) {
        float v = fmaxf(acc[mi][ni][r] + bv, 0.f);
        ((unsigned short*)hL)[(wm + mi * 16 + crow + r) * 520 + col] = f2bf(v);
      }
    }
  }

  // ---- phase 2: msg = h @ w2^T + b2, scatter-add ----
  f32x4 acc2[4][4];
#pragma unroll
  for (int i = 0; i < 4; i++)
#pragma unroll
    for (int j = 0; j < 4; j++) acc2[i][j] = (f32x4){0.f, 0.f, 0.f, 0.f};

  const bf16_t* gW2 = w2b + (size_t)(t >> 2) * 512 + (t & 3) * 8;
  bf16_t* lB2 = sB2 + (size_t)t * 8;

  for (int k0 = 0; k0 < HID; k0 += 32) {
    gl_lds16(gW2,                     lB2);
    gl_lds16(gW2 + (size_t)128 * 512, lB2 + 128 * 32);
    gW2 += 32;
    __syncthreads();   // drains stage AND (first iter) the hL writes
    bf16x8 af2[4], bf2[4];
#pragma unroll
    for (int i = 0; i < 4; i++)
      af2[i] = *(const bf16x8*)(hL + (wm + i * 16 + lrow) * 520 + k0 + kq);
#pragma unroll
    for (int i = 0; i < 4; i++)
      bf2[i] = *(const bf16x8*)(sB2 + (wn2 + i * 16 + lrow) * 32 + kq);
#pragma unroll
    for (int mi = 0; mi < 4; mi++)
#pragma unroll
      for (int ni = 0; ni < 4; ni++)
        acc2[mi][ni] = __builtin_amdgcn_mfma_f32_16x16x32_bf16(af2[mi], bf2[ni], acc2[mi][ni], 0, 0, 0);
    __syncthreads();
  }

#pragma unroll
  for (int mi = 0; mi < 4; mi++) {
    int id4[4];
#pragma unroll
    for (int r = 0; r < 4; r++)
      id4[r] = dstid[(size_t)bm * 128 + wm + mi * 16 + crow + r];
#pragma unroll
    for (int ni = 0; ni < 4; ni++) {
      int gcol = wn2 + ni * 16 + ccol;
      float bv = b2[gcol];
#pragma unroll
      for (int r = 0; r < 4; r++)
        atomicAdd(&sums[(size_t)id4[r] * 256 + gcol], acc2[mi][ni][r] + bv);
    }
  }
}

// ---------------- generic bf16 MFMA GEMM: C[M,N] = A[M,K] @ B[N,K]^T + bias ----------------
// BM=128, BN=256, BK=32, 512 threads = 8 waves (2m x 4n), wave tile 64x64.
// OMODE: 1 = bf16 store (+relu if ACT), 2 = atomicAdd scatter sums[dst[row]*256+col].
// GRUSEL: blockIdx.z==1 -> (A2,bias2,Cout2).
template <int ACT, int OMODE, int GRUSEL>
__global__ __launch_bounds__(512) void gemm_bt2(
    const bf16_t* __restrict__ A, const bf16_t* __restrict__ B,
    const float* __restrict__ bias, void* __restrict__ Cout,
    const bf16_t* __restrict__ A2, const float* __restrict__ bias2,
    void* __restrict__ Cout2,
    const int* __restrict__ dstid, float* __restrict__ sums,
    int M, int N, int K) {
  __shared__ alignas(16) bf16_t sA[128 * 32];
  __shared__ alignas(16) bf16_t sB[256 * 32];

  int bm = blockIdx.y, bn = blockIdx.x;
  if (GRUSEL && blockIdx.z == 1) { A = A2; bias = bias2; Cout = Cout2; }

  const int t = threadIdx.x;
  const int lane = t & 63;
  const int wave = t >> 6;
  const int wm = (wave >> 2) * 64;
  const int wn = (wave & 3) * 64;

  f32x4 acc[4][4];
#pragma unroll
  for (int i = 0; i < 4; i++)
#pragma unroll
    for (int j = 0; j < 4; j++) acc[i][j] = (f32x4){0.f, 0.f, 0.f, 0.f};

  const int rA = t >> 2;
  const int cA = (t & 3) * 8;
  const bf16_t* gA = A + ((size_t)bm * 128 + rA) * K + cA;
  const bf16_t* gB = B + ((size_t)bn * 256 + rA) * K + cA;
  const size_t gB2off = (size_t)128 * K;
  bf16_t* lA = sA + (size_t)t * 8;
  bf16_t* lB = sB + (size_t)t * 8;

  const int lrow = lane & 15;
  const int kq = (lane >> 4) * 8;

  for (int k0 = 0; k0 < K; k0 += 32) {
    gl_lds16(gA, lA);
    gl_lds16(gB, lB);
    gl_lds16(gB + gB2off, lB + 4096);
    gA += 32; gB += 32;
    __syncthreads();
    bf16x8 af[4], bfr[4];
#pragma unroll
    for (int i = 0; i < 4; i++) af[i] = *(const bf16x8*)(sA + (wm + i * 16 + lrow) * 32 + kq);
#pragma unroll
    for (int i = 0; i < 4; i++) bfr[i] = *(const bf16x8*)(sB + (wn + i * 16 + lrow) * 32 + kq);
#pragma unroll
    for (int mi = 0; mi < 4; mi++)
#pragma unroll
      for (int ni = 0; ni < 4; ni++)
        acc[mi][ni] = __builtin_amdgcn_mfma_f32_16x16x32_bf16(af[mi], bfr[ni], acc[mi][ni], 0, 0, 0);
    __syncthreads();
  }

  const int crow = (lane >> 4) * 4;
  const int ccol = lane & 15;
  if (OMODE == 2) {
#pragma unroll
    for (int mi = 0; mi < 4; mi++) {
      int id4[4];
#pragma unroll
      for (int r = 0; r < 4; r++)
        id4[r] = dstid[(size_t)bm * 128 + wm + mi * 16 + crow + r];
#pragma unroll
      for (int ni = 0; ni < 4; ni++) {
        int gcol = wn + ni * 16 + ccol;
        float bv = bias[gcol];
#pragma unroll
        for (int r = 0; r < 4; r++)
          atomicAdd(&sums[(size_t)id4[r] * 256 + gcol], acc[mi][ni][r] + bv);
      }
    }
  } else {
#pragma unroll
    for (int ni = 0; ni < 4; ni++) {
      int gcol = bn * 256 + wn + ni * 16 + ccol;
      float bv = bias[gcol];
#pragma unroll
      for (int mi = 0; mi < 4; mi++) {
#pragma unroll
        for (int r = 0; r < 4; r++) {
          size_t grow = (size_t)bm * 128 + wm + mi * 16 + crow + r;
          float v = acc[mi][ni][r] + bv;
          if (ACT) v = fmaxf(v, 0.f);
          ((unsigned short*)Cout)[grow * N + gcol] = f2bf(v);
        }
      }
    }
  }
}

// ---------------- unique / segment machinery ----------------
__global__ void mark_k(const int* __restrict__ dst, int* __restrict__ flags,
                       float* __restrict__ counts) {
  int e = blockIdx.x * 256 + threadIdx.x;
  if (e < E_EDGES) {
    int id = dst[e];
    flags[id] = 1;
    atomicAdd(&counts[id], 1.0f);
  }
}

__global__ void fill_k(float* __restrict__ uo, int* __restrict__ slot_id) {
  int j = blockIdx.x * 256 + threadIdx.x;
  if (j < NN) { uo[j] = (float)NN; slot_id[j] = -1; }
}

__global__ void scan_k(const int* __restrict__ flags, int* __restrict__ rank) {
  __shared__ int part[1024];
  int t = threadIdx.x;
  int base = t * 32;
  int s = 0;
  for (int i = 0; i < 32; i++) s += flags[base + i];
  part[t] = s;
  __syncthreads();
  for (int off = 1; off < 1024; off <<= 1) {
    int v = (t >= off) ? part[t - off] : 0;
    __syncthreads();
    part[t] += v;
    __syncthreads();
  }
  int run = (t == 0) ? 0 : part[t - 1];
  for (int i = 0; i < 32; i++) { rank[base + i] = run; run += flags[base + i]; }
}

__global__ void scatter_ids(const int* __restrict__ flags, const int* __restrict__ rank,
                            float* __restrict__ uo, int* __restrict__ slot_id) {
  int id = blockIdx.x * 256 + threadIdx.x;
  if (id < NN && flags[id]) {
    int s = rank[id];
    uo[s] = (float)id;
    slot_id[s] = id;
  }
}

__global__ void agg_pack(const int* __restrict__ slot_id, const float* __restrict__ sums,
                         const float* __restrict__ counts, const float* __restrict__ dmem,
                         unsigned short* __restrict__ aggb, unsigned short* __restrict__ prevb) {
  int j = blockIdx.x, t = threadIdx.x;
  int id = slot_id[j];
  float a = 0.f;
  if (id >= 0) a = sums[(size_t)id * 256 + t] / fmaxf(counts[id], 1.f);
  aggb[(size_t)j * 256 + t] = f2bf(a);
  prevb[(size_t)j * 256 + t] = f2bf(dmem[(size_t)j * 256 + t]);
}

__global__ void gru_gate(const unsigned short* __restrict__ gi,
                         const unsigned short* __restrict__ gh,
                         const float* __restrict__ dmem, float* __restrict__ out) {
  int j = blockIdx.x, t = threadIdx.x;
  size_t b = (size_t)j * 768;
  auto bf = [](unsigned short u) { return __uint_as_float((unsigned int)u << 16); };
  float gir = bf(gi[b + t]), giz = bf(gi[b + 256 + t]), gin = bf(gi[b + 512 + t]);
  float ghr = bf(gh[b + t]), ghz = bf(gh[b + 256 + t]), ghn = bf(gh[b + 512 + t]);
  float r = 1.f / (1.f + expf(-(gir + ghr)));
  float z = 1.f / (1.f + expf(-(giz + ghz)));
  float n = tanhf(gin + r * ghn);
  float prev = dmem[(size_t)j * 256 + t];
  out[(size_t)NN + (size_t)j * 256 + t] = (1.f - z) * n + z * prev;
}

extern "C" void kernel_launch(void* const* d_in, const int* in_sizes, int n_in,
                              void* d_out, int out_size, void* d_ws, size_t ws_size,
                              hipStream_t stream) {
  const float* rel  = (const float*)d_in[0];
  const float* src  = (const float*)d_in[1];
  const float* dmem = (const float*)d_in[2];
  const float* edge = (const float*)d_in[3];
  const int*   dst  = (const int*)d_in[4];
  const float* tw   = (const float*)d_in[5];
  const float* tb   = (const float*)d_in[6];
  const float* w1   = (const float*)d_in[7];
  const float* b1   = (const float*)d_in[8];
  const float* w2   = (const float*)d_in[9];
  const float* b2   = (const float*)d_in[10];
  const float* wih  = (const float*)d_in[11];
  const float* whh  = (const float*)d_in[12];
  const float* bih  = (const float*)d_in[13];
  const float* bhh  = (const float*)d_in[14];

  char* ws = (char*)d_ws;
  size_t o = 0;
  auto take = [&](size_t bytes) -> char* {
    char* p = ws + o;
    o += (bytes + 255) & ~(size_t)255;
    return p;
  };

  unsigned short* gib   = (unsigned short*)take((size_t)NN * 768 * 2);
  unsigned short* ghb   = (unsigned short*)take((size_t)NN * 768 * 2);
  float* sums           = (float*)take((size_t)NN * 256 * 4);
  float* counts         = (float*)take((size_t)NN * 4);
  int*   flags          = (int*)take((size_t)NN * 4);
  int*   rank           = (int*)take((size_t)NN * 4);
  int*   slot_id        = (int*)take((size_t)NN * 4);
  unsigned short* aggb  = (unsigned short*)take((size_t)NN * 256 * 2);
  unsigned short* prevb = (unsigned short*)take((size_t)NN * 256 * 2);
  unsigned short* w1b   = (unsigned short*)take((size_t)HID * INDIM * 2);
  unsigned short* w2b   = (unsigned short*)take((size_t)MSGD * HID * 2);
  unsigned short* wihb  = (unsigned short*)take((size_t)768 * 256 * 2);
  unsigned short* whhb  = (unsigned short*)take((size_t)768 * 256 * 2);

  float* outf = (float*)d_out;

  hipMemsetAsync(sums, 0, (size_t)NN * 256 * 4, stream);
  hipMemsetAsync(counts, 0, (size_t)NN * 4, stream);
  hipMemsetAsync(flags, 0, (size_t)NN * 4, stream);

  int n1 = HID * INDIM;
  int n2 = MSGD * HID;
  int n3 = 768 * 256;
  cvt_bf16<<<(n1 + 255) / 256, 256, 0, stream>>>(w1, w1b, n1);
  cvt_bf16<<<(n2 + 255) / 256, 256, 0, stream>>>(w2, w2b, n2);
  cvt_bf16<<<(n3 + 255) / 256, 256, 0, stream>>>(wih, wihb, n3);
  cvt_bf16<<<(n3 + 255) / 256, 256, 0, stream>>>(whh, whhb, n3);

  mark_k<<<E_EDGES / 256, 256, 0, stream>>>(dst, flags, counts);

  // fused: h = relu(X@w1^T+b1) kept in LDS; msg = h@w2^T+b2 scattered into sums
  gemm12_fused<<<dim3(E_EDGES / 128), 512, 0, stream>>>(
      src, dmem, edge, rel, tw, tb, (const bf16_t*)w1b, b1,
      (const bf16_t*)w2b, b2, dst, sums);

  fill_k<<<NN / 256, 256, 0, stream>>>(outf, slot_id);
  scan_k<<<1, 1024, 0, stream>>>(flags, rank);
  scatter_ids<<<NN / 256, 256, 0, stream>>>(flags, rank, outf, slot_id);
  agg_pack<<<NN, 256, 0, stream>>>(slot_id, sums, counts, dmem, aggb, prevb);

  // gi = agg @ w_ih^T + b_ih ; gh = prev @ w_hh^T + b_hh  (bf16 out)
  gemm_bt2<0, 1, 1><<<dim3(768 / 256, NN / 128, 2), 512, 0, stream>>>(
      (const bf16_t*)aggb, (const bf16_t*)wihb, bih, gib,
      (const bf16_t*)prevb, bhh, ghb, nullptr, nullptr, NN, 768, 256);

  gru_gate<<<NN, 256, 0, stream>>>(gib, ghb, dmem, outf);
}

// Round 2
// 703.204 us; speedup vs baseline: 1.0285x; 1.0285x over previous
//
#include <hip/hip_runtime.h>
#include <math.h>
#include <stdint.h>

#define E_EDGES 131072
#define NN 32768      // NUM_NODES
#define DMEM 256
#define DEDGE 128
#define TDIM 64
#define HID 512
#define MSGD 256
#define INDIM 704     // 2*256+128+64

typedef __bf16 bf16_t;
typedef bf16_t bf16x8 __attribute__((ext_vector_type(8)));
typedef float f32x4 __attribute__((ext_vector_type(4)));

__device__ __forceinline__ unsigned short f2bf(float f) {
  unsigned int u = __float_as_uint(f);
  u += 0x7FFF + ((u >> 16) & 1);   // round-to-nearest-even
  return (unsigned short)(u >> 16);
}

__device__ __forceinline__ void gl_lds16(const bf16_t* g, bf16_t* l) {
  __builtin_amdgcn_global_load_lds(
      (__attribute__((address_space(1))) void*)(g),
      (__attribute__((address_space(3))) void*)(l), 16, 0, 0);
}

__global__ void cvt_bf16(const float* __restrict__ in, unsigned short* __restrict__ out, int n) {
  int i = blockIdx.x * 256 + threadIdx.x;
  if (i < n) out[i] = f2bf(in[i]);
}

// ---------------- fused GEMM1+GEMM2 over dst-sorted edges ----------------
// Edge rows are permuted so dst ids are sorted; each block owns 128 sorted rows.
// Phase 1: h[128][512] = relu([src|dst|edge|cos(rel*tw+tb)] @ w1^T + b1)  (gathered A)
// Phase 2: msg[128][256] = h @ w2^T (+b2), h kept in LDS.
// Epilogue: msg -> LDS f32, segment-reduce equal-dst runs, plain store for
// interior nodes, atomicAdd only for runs touching the block boundary.
__global__ __launch_bounds__(512) void gemm12_fused(
    const float* __restrict__ src, const float* __restrict__ dmem,
    const float* __restrict__ edge, const float* __restrict__ rel,
    const float* __restrict__ tw, const float* __restrict__ tb,
    const bf16_t* __restrict__ w1b, const float* __restrict__ b1,
    const bf16_t* __restrict__ w2b, const float* __restrict__ b2,
    const int* __restrict__ perm, const int* __restrict__ dsts,
    float* __restrict__ sums) {
  // 149,504 B union:
  //   phase 1:  sA [128][32] @0 (8KB),  sB [512][32] @8KB (32KB)
  //   phase 1.5/2: hL [128][520] @0 (130KB), sB2 [256][32] @130KB (16KB)
  //   epilogue: msgL f32 [128][260] @0 (133KB)
  __shared__ alignas(16) bf16_t smem[74752];
  __shared__ float sTW[64], sTB[64], sRel[128];
  __shared__ int sPerm[128], sDst[128];
  bf16_t* sA  = smem;                 // [128][32]
  bf16_t* sB  = smem + 128 * 32;      // [512][32]
  bf16_t* hL  = smem;                 // [128][520]
  bf16_t* sB2 = smem + 128 * 520;     // [256][32]

  const int bm = blockIdx.x;          // 1024 blocks
  const int t = threadIdx.x;
  const int lane = t & 63;
  const int wave = t >> 6;
  const int wm  = (wave >> 2) * 64;   // 0 / 64
  const int wn1 = (wave & 3) * 128;   // phase-1 wave col (tile 64x128)
  const int wn2 = (wave & 3) * 64;    // phase-2 wave col (tile 64x64)

  if (t < 64) { sTW[t] = tw[t]; sTB[t] = tb[t]; }
  if (t < 128) {
    int e = perm[bm * 128 + t];
    sPerm[t] = e;
    sRel[t] = rel[e];
    sDst[t] = dsts[bm * 128 + t];
  }
  __syncthreads();

  f32x4 acc[4][8];
#pragma unroll
  for (int i = 0; i < 4; i++)
#pragma unroll
    for (int j = 0; j < 8; j++) acc[i][j] = (f32x4){0.f, 0.f, 0.f, 0.f};

  // A staging: thread -> (row ar, col-group ac of 8); row gathered via perm
  const int ar = t >> 2;           // 0..127
  const int ac = (t & 3) * 8;      // 0,8,16,24
  const size_t arow = (size_t)sPerm[ar];
  // B staging: rows 0..511 in 4 gl_lds16 waves-of-128-rows
  const bf16_t* gB = w1b + (size_t)(t >> 2) * 704 + (t & 3) * 8;
  bf16_t* lB = sB + (size_t)t * 8;

  const int lrow = lane & 15;
  const int kq = (lane >> 4) * 8;

  for (int k0 = 0; k0 < INDIM; k0 += 32) {
    gl_lds16(gB,                     lB);
    gl_lds16(gB + (size_t)128 * 704, lB + 128 * 32);
    gl_lds16(gB + (size_t)256 * 704, lB + 256 * 32);
    gl_lds16(gB + (size_t)384 * 704, lB + 384 * 32);
    gB += 32;

    bf16x8 av;
    if (k0 < 640) {
      const float* p;
      if (k0 < 256)      p = src  + arow * 256 + k0 + ac;
      else if (k0 < 512) p = dmem + arow * 256 + (k0 - 256) + ac;
      else               p = edge + arow * 128 + (k0 - 512) + ac;
      f32x4 u = *(const f32x4*)p;
      f32x4 v = *(const f32x4*)(p + 4);
      av[0] = (bf16_t)u[0]; av[1] = (bf16_t)u[1]; av[2] = (bf16_t)u[2]; av[3] = (bf16_t)u[3];
      av[4] = (bf16_t)v[0]; av[5] = (bf16_t)v[1]; av[6] = (bf16_t)v[2]; av[7] = (bf16_t)v[3];
    } else {
      float rv = sRel[ar];
      int kk = (k0 - 640) + ac;
#pragma unroll
      for (int j = 0; j < 8; j++)
        av[j] = (bf16_t)cosf(rv * sTW[kk + j] + sTB[kk + j]);
    }
    *(bf16x8*)(sA + ar * 32 + ac) = av;

    __syncthreads();
    bf16x8 af[4], bfr[8];
#pragma unroll
    for (int i = 0; i < 4; i++) af[i] = *(const bf16x8*)(sA + (wm + i * 16 + lrow) * 32 + kq);
#pragma unroll
    for (int i = 0; i < 8; i++) bfr[i] = *(const bf16x8*)(sB + (wn1 + i * 16 + lrow) * 32 + kq);
#pragma unroll
    for (int mi = 0; mi < 4; mi++)
#pragma unroll
      for (int ni = 0; ni < 8; ni++)
        acc[mi][ni] = __builtin_amdgcn_mfma_f32_16x16x32_bf16(af[mi], bfr[ni], acc[mi][ni], 0, 0, 0);
    __syncthreads();
  }

  // ---- phase 1.5: relu+bias, h -> LDS (bf16, padded stride 520) ----
  const int crow = (lane >> 4) * 4;
  const int ccol = lane & 15;
#pragma unroll
  for (int ni = 0; ni < 8; ni++) {
    int col = wn1 + ni * 16 + ccol;
    float bv = b1[col];
#pragma unroll
    for (int mi = 0; mi < 4; mi++) {
#pragma unroll
      for (int r = 0; r < 4; r++) {
        float v = fmaxf(acc[mi][ni][r] + bv, 0.f);
        ((unsigned short*)hL)[(wm + mi * 16 + crow + r) * 520 + col] = f2bf(v);
      }
    }
  }

  // ---- phase 2: msg = h @ w2^T + b2 ----
  f32x4 acc2[4][4];
#pragma unroll
  for (int i = 0; i < 4; i++)
#pragma unroll
    for (int j = 0; j < 4; j++) acc2[i][j] = (f32x4){0.f, 0.f, 0.f, 0.f};

  const bf16_t* gW2 = w2b + (size_t)(t >> 2) * 512 + (t & 3) * 8;
  bf16_t* lB2 = sB2 + (size_t)t * 8;

  for (int k0 = 0; k0 < HID; k0 += 32) {
    gl_lds16(gW2,                     lB2);
    gl_lds16(gW2 + (size_t)128 * 512, lB2 + 128 * 32);
    gW2 += 32;
    __syncthreads();   // drains stage AND (first iter) the hL writes
    bf16x8 af2[4], bf2[4];
#pragma unroll
    for (int i = 0; i < 4; i++)
      af2[i] = *(const bf16x8*)(hL + (wm + i * 16 + lrow) * 520 + k0 + kq);
#pragma unroll
    for (int i = 0; i < 4; i++)
      bf2[i] = *(const bf16x8*)(sB2 + (wn2 + i * 16 + lrow) * 32 + kq);
#pragma unroll
    for (int mi = 0; mi < 4; mi++)
#pragma unroll
      for (int ni = 0; ni < 4; ni++)
        acc2[mi][ni] = __builtin_amdgcn_mfma_f32_16x16x32_bf16(af2[mi], bf2[ni], acc2[mi][ni], 0, 0, 0);
    __syncthreads();
  }

  // ---- epilogue: msg -> LDS f32, segment-reduce sorted runs ----
  {
    float* msgL = (float*)smem;      // [128][260] padded
#pragma unroll
    for (int ni = 0; ni < 4; ni++) {
      int gcol = wn2 + ni * 16 + ccol;
      float bv = b2[gcol];
#pragma unroll
      for (int mi = 0; mi < 4; mi++) {
#pragma unroll
        for (int r = 0; r < 4; r++)
          msgL[(wm + mi * 16 + crow + r) * 260 + gcol] = acc2[mi][ni][r] + bv;
      }
    }
    __syncthreads();

    const int c = t & 255;           // column
    const int h = t >> 8;            // row half 0/1 (wave-uniform)
    int r = h * 64;
    const int rend = h * 64 + 64;
    while (r < rend) {
      int id = sDst[r];
      if (r > 0 && sDst[r - 1] == id) { r++; continue; }  // mid-run: owned by earlier head
      float s2 = msgL[r * 260 + c];
      int rr = r + 1;
      while (rr < 128 && sDst[rr] == id) { s2 += msgL[rr * 260 + c]; rr++; }
      if (r == 0 || rr == 128)       // run may continue in neighbor block
        atomicAdd(&sums[(size_t)id * 256 + c], s2);
      else                           // node fully owned by this block
        sums[(size_t)id * 256 + c] = s2;
      r = rr;
    }
  }
}

// ---------------- generic bf16 MFMA GEMM: C[M,N] = A[M,K] @ B[N,K]^T + bias ----------------
template <int ACT, int OMODE, int GRUSEL>
__global__ __launch_bounds__(512) void gemm_bt2(
    const bf16_t* __restrict__ A, const bf16_t* __restrict__ B,
    const float* __restrict__ bias, void* __restrict__ Cout,
    const bf16_t* __restrict__ A2, const float* __restrict__ bias2,
    void* __restrict__ Cout2,
    const int* __restrict__ dstid, float* __restrict__ sums,
    int M, int N, int K) {
  __shared__ alignas(16) bf16_t sA[128 * 32];
  __shared__ alignas(16) bf16_t sB[256 * 32];

  int bm = blockIdx.y, bn = blockIdx.x;
  if (GRUSEL && blockIdx.z == 1) { A = A2; bias = bias2; Cout = Cout2; }

  const int t = threadIdx.x;
  const int lane = t & 63;
  const int wave = t >> 6;
  const int wm = (wave >> 2) * 64;
  const int wn = (wave & 3) * 64;

  f32x4 acc[4][4];
#pragma unroll
  for (int i = 0; i < 4; i++)
#pragma unroll
    for (int j = 0; j < 4; j++) acc[i][j] = (f32x4){0.f, 0.f, 0.f, 0.f};

  const int rA = t >> 2;
  const int cA = (t & 3) * 8;
  const bf16_t* gA = A + ((size_t)bm * 128 + rA) * K + cA;
  const bf16_t* gB = B + ((size_t)bn * 256 + rA) * K + cA;
  const size_t gB2off = (size_t)128 * K;
  bf16_t* lA = sA + (size_t)t * 8;
  bf16_t* lB = sB + (size_t)t * 8;

  const int lrow = lane & 15;
  const int kq = (lane >> 4) * 8;

  for (int k0 = 0; k0 < K; k0 += 32) {
    gl_lds16(gA, lA);
    gl_lds16(gB, lB);
    gl_lds16(gB + gB2off, lB + 4096);
    gA += 32; gB += 32;
    __syncthreads();
    bf16x8 af[4], bfr[4];
#pragma unroll
    for (int i = 0; i < 4; i++) af[i] = *(const bf16x8*)(sA + (wm + i * 16 + lrow) * 32 + kq);
#pragma unroll
    for (int i = 0; i < 4; i++) bfr[i] = *(const bf16x8*)(sB + (wn + i * 16 + lrow) * 32 + kq);
#pragma unroll
    for (int mi = 0; mi < 4; mi++)
#pragma unroll
      for (int ni = 0; ni < 4; ni++)
        acc[mi][ni] = __builtin_amdgcn_mfma_f32_16x16x32_bf16(af[mi], bfr[ni], acc[mi][ni], 0, 0, 0);
    __syncthreads();
  }

  const int crow = (lane >> 4) * 4;
  const int ccol = lane & 15;
  if (OMODE == 2) {
#pragma unroll
    for (int mi = 0; mi < 4; mi++) {
      int id4[4];
#pragma unroll
      for (int r = 0; r < 4; r++)
        id4[r] = dstid[(size_t)bm * 128 + wm + mi * 16 + crow + r];
#pragma unroll
      for (int ni = 0; ni < 4; ni++) {
        int gcol = wn + ni * 16 + ccol;
        float bv = bias[gcol];
#pragma unroll
        for (int r = 0; r < 4; r++)
          atomicAdd(&sums[(size_t)id4[r] * 256 + gcol], acc[mi][ni][r] + bv);
      }
    }
  } else {
#pragma unroll
    for (int ni = 0; ni < 4; ni++) {
      int gcol = bn * 256 + wn + ni * 16 + ccol;
      float bv = bias[gcol];
#pragma unroll
      for (int mi = 0; mi < 4; mi++) {
#pragma unroll
        for (int r = 0; r < 4; r++) {
          size_t grow = (size_t)bm * 128 + wm + mi * 16 + crow + r;
          float v = acc[mi][ni][r] + bv;
          if (ACT) v = fmaxf(v, 0.f);
          ((unsigned short*)Cout)[grow * N + gcol] = f2bf(v);
        }
      }
    }
  }
}

// ---------------- unique / sort machinery ----------------
__global__ void mark_k(const int* __restrict__ dst, int* __restrict__ icnt) {
  int e = blockIdx.x * 256 + threadIdx.x;
  if (e < E_EDGES) atomicAdd(&icnt[dst[e]], 1);
}

__global__ void fill_k(float* __restrict__ uo, int* __restrict__ slot_id) {
  int j = blockIdx.x * 256 + threadIdx.x;
  if (j < NN) { uo[j] = (float)NN; slot_id[j] = -1; }
}

// dual scan over icnt: rank = exclusive scan of (icnt>0), offs = exclusive scan of icnt
__global__ void scan2_k(const int* __restrict__ icnt, int* __restrict__ rank,
                        int* __restrict__ offs) {
  __shared__ int pf[1024], pc[1024];
  int t = threadIdx.x;
  int base = t * 32;
  int sf = 0, sc = 0;
  for (int i = 0; i < 32; i++) { int v = icnt[base + i]; sf += (v > 0); sc += v; }
  pf[t] = sf; pc[t] = sc;
  __syncthreads();
  for (int off = 1; off < 1024; off <<= 1) {
    int vf = (t >= off) ? pf[t - off] : 0;
    int vc = (t >= off) ? pc[t - off] : 0;
    __syncthreads();
    pf[t] += vf; pc[t] += vc;
    __syncthreads();
  }
  int runf = (t == 0) ? 0 : pf[t - 1];
  int runc = (t == 0) ? 0 : pc[t - 1];
  for (int i = 0; i < 32; i++) {
    int v = icnt[base + i];
    rank[base + i] = runf; runf += (v > 0);
    offs[base + i] = runc; runc += v;
  }
}

__global__ void scatter_ids(const int* __restrict__ icnt, const int* __restrict__ rank,
                            float* __restrict__ uo, int* __restrict__ slot_id) {
  int id = blockIdx.x * 256 + threadIdx.x;
  if (id < NN && icnt[id] > 0) {
    int s = rank[id];
    uo[s] = (float)id;
    slot_id[s] = id;
  }
}

// counting-sort: perm[pos] = edge index, dsts[pos] = its dst id (sorted)
__global__ void scatter_edges(const int* __restrict__ dst, const int* __restrict__ offs,
                              int* __restrict__ cursor, int* __restrict__ perm,
                              int* __restrict__ dsts) {
  int e = blockIdx.x * 256 + threadIdx.x;
  if (e < E_EDGES) {
    int id = dst[e];
    int pos = offs[id] + atomicAdd(&cursor[id], 1);
    perm[pos] = e;
    dsts[pos] = id;
  }
}

__global__ void agg_pack(const int* __restrict__ slot_id, const float* __restrict__ sums,
                         const int* __restrict__ icnt, const float* __restrict__ dmem,
                         unsigned short* __restrict__ aggb, unsigned short* __restrict__ prevb) {
  int j = blockIdx.x, t = threadIdx.x;
  int id = slot_id[j];
  float a = 0.f;
  if (id >= 0) a = sums[(size_t)id * 256 + t] / fmaxf((float)icnt[id], 1.f);
  aggb[(size_t)j * 256 + t] = f2bf(a);
  prevb[(size_t)j * 256 + t] = f2bf(dmem[(size_t)j * 256 + t]);
}

__global__ void gru_gate(const unsigned short* __restrict__ gi,
                         const unsigned short* __restrict__ gh,
                         const float* __restrict__ dmem, float* __restrict__ out) {
  int j = blockIdx.x, t = threadIdx.x;
  size_t b = (size_t)j * 768;
  auto bf = [](unsigned short u) { return __uint_as_float((unsigned int)u << 16); };
  float gir = bf(gi[b + t]), giz = bf(gi[b + 256 + t]), gin = bf(gi[b + 512 + t]);
  float ghr = bf(gh[b + t]), ghz = bf(gh[b + 256 + t]), ghn = bf(gh[b + 512 + t]);
  float r = 1.f / (1.f + expf(-(gir + ghr)));
  float z = 1.f / (1.f + expf(-(giz + ghz)));
  float n = tanhf(gin + r * ghn);
  float prev = dmem[(size_t)j * 256 + t];
  out[(size_t)NN + (size_t)j * 256 + t] = (1.f - z) * n + z * prev;
}

extern "C" void kernel_launch(void* const* d_in, const int* in_sizes, int n_in,
                              void* d_out, int out_size, void* d_ws, size_t ws_size,
                              hipStream_t stream) {
  const float* rel  = (const float*)d_in[0];
  const float* src  = (const float*)d_in[1];
  const float* dmem = (const float*)d_in[2];
  const float* edge = (const float*)d_in[3];
  const int*   dst  = (const int*)d_in[4];
  const float* tw   = (const float*)d_in[5];
  const float* tb   = (const float*)d_in[6];
  const float* w1   = (const float*)d_in[7];
  const float* b1   = (const float*)d_in[8];
  const float* w2   = (const float*)d_in[9];
  const float* b2   = (const float*)d_in[10];
  const float* wih  = (const float*)d_in[11];
  const float* whh  = (const float*)d_in[12];
  const float* bih  = (const float*)d_in[13];
  const float* bhh  = (const float*)d_in[14];

  char* ws = (char*)d_ws;
  size_t o = 0;
  auto take = [&](size_t bytes) -> char* {
    char* p = ws + o;
    o += (bytes + 255) & ~(size_t)255;
    return p;
  };

  unsigned short* gib   = (unsigned short*)take((size_t)NN * 768 * 2);
  unsigned short* ghb   = (unsigned short*)take((size_t)NN * 768 * 2);
  float* sums           = (float*)take((size_t)NN * 256 * 4);
  int*   icnt           = (int*)take((size_t)NN * 4);
  int*   rank           = (int*)take((size_t)NN * 4);
  int*   offs           = (int*)take((size_t)NN * 4);
  int*   cursor         = (int*)take((size_t)NN * 4);
  int*   slot_id        = (int*)take((size_t)NN * 4);
  int*   perm           = (int*)take((size_t)E_EDGES * 4);
  int*   dsts           = (int*)take((size_t)E_EDGES * 4);
  unsigned short* aggb  = (unsigned short*)take((size_t)NN * 256 * 2);
  unsigned short* prevb = (unsigned short*)take((size_t)NN * 256 * 2);
  unsigned short* w1b   = (unsigned short*)take((size_t)HID * INDIM * 2);
  unsigned short* w2b   = (unsigned short*)take((size_t)MSGD * HID * 2);
  unsigned short* wihb  = (unsigned short*)take((size_t)768 * 256 * 2);
  unsigned short* whhb  = (unsigned short*)take((size_t)768 * 256 * 2);

  float* outf = (float*)d_out;

  hipMemsetAsync(sums, 0, (size_t)NN * 256 * 4, stream);
  hipMemsetAsync(icnt, 0, (size_t)NN * 4, stream);
  hipMemsetAsync(cursor, 0, (size_t)NN * 4, stream);

  int n1 = HID * INDIM;
  int n2 = MSGD * HID;
  int n3 = 768 * 256;
  cvt_bf16<<<(n1 + 255) / 256, 256, 0, stream>>>(w1, w1b, n1);
  cvt_bf16<<<(n2 + 255) / 256, 256, 0, stream>>>(w2, w2b, n2);
  cvt_bf16<<<(n3 + 255) / 256, 256, 0, stream>>>(wih, wihb, n3);
  cvt_bf16<<<(n3 + 255) / 256, 256, 0, stream>>>(whh, whhb, n3);

  mark_k<<<E_EDGES / 256, 256, 0, stream>>>(dst, icnt);
  scan2_k<<<1, 1024, 0, stream>>>(icnt, rank, offs);
  scatter_edges<<<E_EDGES / 256, 256, 0, stream>>>(dst, offs, cursor, perm, dsts);

  fill_k<<<NN / 256, 256, 0, stream>>>(outf, slot_id);
  scatter_ids<<<NN / 256, 256, 0, stream>>>(icnt, rank, outf, slot_id);

  // fused: h = relu(X@w1^T+b1) in LDS; msg = h@w2^T+b2 segment-reduced into sums
  gemm12_fused<<<dim3(E_EDGES / 128), 512, 0, stream>>>(
      src, dmem, edge, rel, tw, tb, (const bf16_t*)w1b, b1,
      (const bf16_t*)w2b, b2, perm, dsts, sums);

  agg_pack<<<NN, 256, 0, stream>>>(slot_id, sums, icnt, dmem, aggb, prevb);

  // gi = agg @ w_ih^T + b_ih ; gh = prev @ w_hh^T + b_hh  (bf16 out)
  gemm_bt2<0, 1, 1><<<dim3(768 / 256, NN / 128, 2), 512, 0, stream>>>(
      (const bf16_t*)aggb, (const bf16_t*)wihb, bih, gib,
      (const bf16_t*)prevb, bhh, ghb, nullptr, nullptr, NN, 768, 256);

  gru_gate<<<NN, 256, 0, stream>>>(gib, ghb, dmem, outf);
}

// Round 4
// 651.579 us; speedup vs baseline: 1.1100x; 1.0792x over previous
//
#include <hip/hip_runtime.h>
#include <math.h>
#include <stdint.h>

#define E_EDGES 131072
#define NN 32768      // NUM_NODES
#define DMEM 256
#define DEDGE 128
#define TDIM 64
#define HID 512
#define MSGD 256
#define INDIM 704     // 2*256+128+64

typedef __bf16 bf16_t;
typedef bf16_t bf16x8 __attribute__((ext_vector_type(8)));
typedef float f32x4 __attribute__((ext_vector_type(4)));

__device__ __forceinline__ unsigned short f2bf(float f) {
  unsigned int u = __float_as_uint(f);
  u += 0x7FFF + ((u >> 16) & 1);   // round-to-nearest-even
  return (unsigned short)(u >> 16);
}

__device__ __forceinline__ void gl_lds16(const bf16_t* g, bf16_t* l) {
  __builtin_amdgcn_global_load_lds(
      (__attribute__((address_space(1))) void*)(g),
      (__attribute__((address_space(3))) void*)(l), 16, 0, 0);
}

__global__ void cvt_bf16(const float* __restrict__ in, unsigned short* __restrict__ out, int n) {
  int i = blockIdx.x * 256 + threadIdx.x;
  if (i < n) out[i] = f2bf(in[i]);
}

// Granule swizzle for [R][32]-bf16 LDS tiles (row = 4 granules of 16B):
//   physical granule p holds logical granule p ^ ((row>>1)&3).
//   Staging writes LINEAR (thread t -> row t>>2, granule t&3) and fetches the
//   global source at swizzled column gs8 = ((t&3)^((t>>3)&3))*8 (per-thread const).
//   Frag reads use kqs = ((lane>>4)^((lane>>1)&3))*8  (since (row>>1)&3 ==
//   (lane>>1)&3 for row = 16*m + (lane&15)).
// Result: each 16-lane read group spans all 32 banks -> 2-way (free).

// ---------------- fused GEMM1+GEMM2 over dst-sorted edges, pipelined ----------------
__global__ __launch_bounds__(512) void gemm12_fused(
    const float* __restrict__ src, const float* __restrict__ dmem,
    const float* __restrict__ edge, const float* __restrict__ rel,
    const float* __restrict__ tw, const float* __restrict__ tb,
    const bf16_t* __restrict__ w1b, const float* __restrict__ b1,
    const bf16_t* __restrict__ w2b, const float* __restrict__ b2,
    const int* __restrict__ perm, const int* __restrict__ dsts,
    float* __restrict__ sums) {
  // 149,504 B union (74752 bf16):
  //   phase 1 (dbuf): A0@0(4096) A1@4096 B0@8192(16384) B1@24576 -> 40960 elems
  //   phase 1.5/2:    hL [128][520] @0 (66560), sB2 [256][32] @66560 (8192)
  //   epilogue:       msgL f32 [128][260] @0 (66560 f32-equiv bytes = 133,120)
  __shared__ alignas(16) bf16_t smem[74752];
  __shared__ float sTW[64], sTB[64], sRel[128];
  __shared__ int sPerm[128], sDst[128];
  bf16_t* hL  = smem;                 // [128][520]
  bf16_t* sB2 = smem + 66560;         // [256][32]

  const int bm = blockIdx.x;          // 1024 blocks
  const int t = threadIdx.x;
  const int lane = t & 63;
  const int wave = t >> 6;
  const int wm  = (wave >> 2) * 64;   // 0 / 64
  const int wn1 = (wave & 3) * 128;   // phase-1 wave col (tile 64x128)
  const int wn2 = (wave & 3) * 64;    // phase-2 wave col (tile 64x64)

  if (t < 64) { sTW[t] = tw[t]; sTB[t] = tb[t]; }
  if (t < 128) {
    int e = perm[bm * 128 + t];
    sPerm[t] = e;
    sRel[t] = rel[e];
    sDst[t] = dsts[bm * 128 + t];
  }
  __syncthreads();

  f32x4 acc[4][8];
#pragma unroll
  for (int i = 0; i < 4; i++)
#pragma unroll
    for (int j = 0; j < 8; j++) acc[i][j] = (f32x4){0.f, 0.f, 0.f, 0.f};

  const int ar   = t >> 2;                          // staging row 0..127
  const int lin8 = (t & 3) * 8;                     // linear granule offset
  const int gs8  = (((t & 3) ^ ((t >> 3) & 3))) * 8; // swizzled source granule
  const size_t arow = (size_t)sPerm[ar];
  const float rv0 = sRel[ar];
  const bf16_t* gB = w1b + (size_t)ar * 704 + gs8;

  const int lrow = lane & 15;
  const int kqs  = ((lane >> 4) ^ ((lane >> 1) & 3)) * 8;  // swizzled frag granule
  const int kql  = (lane >> 4) * 8;                        // linear (for hL)

  // ---- phase-1 prologue: stage chunk 0 into buf0 ----
  {
    f32x4 u = *(const f32x4*)(src + arow * 256 + gs8);
    f32x4 v = *(const f32x4*)(src + arow * 256 + gs8 + 4);
    bf16_t* lB = smem + 8192 + (size_t)t * 8;
    gl_lds16(gB,                     lB);
    gl_lds16(gB + (size_t)128 * 704, lB + 4096);
    gl_lds16(gB + (size_t)256 * 704, lB + 8192);
    gl_lds16(gB + (size_t)384 * 704, lB + 12288);
    gB += 32;
    bf16x8 av;
    av[0] = (bf16_t)u[0]; av[1] = (bf16_t)u[1]; av[2] = (bf16_t)u[2]; av[3] = (bf16_t)u[3];
    av[4] = (bf16_t)v[0]; av[5] = (bf16_t)v[1]; av[6] = (bf16_t)v[2]; av[7] = (bf16_t)v[3];
    *(bf16x8*)(smem + ar * 32 + lin8) = av;
  }
  __syncthreads();

  int cur = 0;
  for (int c = 0; c < 22; ++c) {
    const int cn = c + 1;
    const bool more = (cn < 22);
    const bool ld   = (cn < 20);       // chunks 20,21 are the cos columns
    f32x4 u, v;
    if (ld) {                          // issue next A loads first (HBM latency)
      const int col = cn * 32;
      const float* p;
      if (col < 256)      p = src  + arow * 256 + col + gs8;
      else if (col < 512) p = dmem + arow * 256 + (col - 256) + gs8;
      else                p = edge + arow * 128 + (col - 512) + gs8;
      u = *(const f32x4*)p;
      v = *(const f32x4*)(p + 4);
    }
    const int nxt = cur ^ 1;
    if (more) {                        // issue next w1 tile into other buffer
      bf16_t* lB = smem + (nxt ? 24576 : 8192) + (size_t)t * 8;
      gl_lds16(gB,                     lB);
      gl_lds16(gB + (size_t)128 * 704, lB + 4096);
      gl_lds16(gB + (size_t)256 * 704, lB + 8192);
      gl_lds16(gB + (size_t)384 * 704, lB + 12288);
      gB += 32;
    }

    const bf16_t* bA = smem + (cur ? 4096 : 0);
    const bf16_t* bB = smem + (cur ? 24576 : 8192);
    bf16x8 af[4], bfr[8];
#pragma unroll
    for (int i = 0; i < 4; i++) af[i]  = *(const bf16x8*)(bA + (wm  + i * 16 + lrow) * 32 + kqs);
#pragma unroll
    for (int i = 0; i < 8; i++) bfr[i] = *(const bf16x8*)(bB + (wn1 + i * 16 + lrow) * 32 + kqs);

    __builtin_amdgcn_s_setprio(1);
#pragma unroll
    for (int mi = 0; mi < 4; mi++)
#pragma unroll
      for (int ni = 0; ni < 8; ni++)
        acc[mi][ni] = __builtin_amdgcn_mfma_f32_16x16x32_bf16(af[mi], bfr[ni], acc[mi][ni], 0, 0, 0);
    __builtin_amdgcn_s_setprio(0);

    if (more) {
      bf16x8 av;
      if (ld) {
        av[0] = (bf16_t)u[0]; av[1] = (bf16_t)u[1]; av[2] = (bf16_t)u[2]; av[3] = (bf16_t)u[3];
        av[4] = (bf16_t)v[0]; av[5] = (bf16_t)v[1]; av[6] = (bf16_t)v[2]; av[7] = (bf16_t)v[3];
      } else {
        int kk = cn * 32 - 640 + gs8;
#pragma unroll
        for (int j = 0; j < 8; j++)
          av[j] = (bf16_t)cosf(rv0 * sTW[kk + j] + sTB[kk + j]);
      }
      *(bf16x8*)(smem + (nxt ? 4096 : 0) + ar * 32 + lin8) = av;
    }
    __syncthreads();
    cur = nxt;
  }

  // ---- phase 1.5: relu+bias, h -> LDS (bf16, padded stride 520, linear) ----
  const int crow = (lane >> 4) * 4;
  const int ccol = lane & 15;
#pragma unroll
  for (int ni = 0; ni < 8; ni++) {
    int col = wn1 + ni * 16 + ccol;
    float bv = b1[col];
#pragma unroll
    for (int mi = 0; mi < 4; mi++) {
#pragma unroll
      for (int r = 0; r < 4; r++) {
        float v = fmaxf(acc[mi][ni][r] + bv, 0.f);
        ((unsigned short*)hL)[(wm + mi * 16 + crow + r) * 520 + col] = f2bf(v);
      }
    }
  }

  // ---- phase 2: msg = h @ w2^T + b2 (single-buffered sB2, 2 barriers) ----
  f32x4 acc2[4][4];
#pragma unroll
  for (int i = 0; i < 4; i++)
#pragma unroll
    for (int j = 0; j < 4; j++) acc2[i][j] = (f32x4){0.f, 0.f, 0.f, 0.f};

  const bf16_t* gW2 = w2b + (size_t)ar * 512 + gs8;
  bf16_t* lB2 = sB2 + (size_t)t * 8;

  gl_lds16(gW2,                     lB2);
  gl_lds16(gW2 + (size_t)128 * 512, lB2 + 4096);
  gW2 += 32;
  __syncthreads();   // drains hL ds_writes + sB2 gl_lds

  for (int k0 = 0; k0 < HID; k0 += 32) {
    bf16x8 af2[4], bf2[4];
#pragma unroll
    for (int i = 0; i < 4; i++)
      af2[i] = *(const bf16x8*)(hL + (wm + i * 16 + lrow) * 520 + k0 + kql);
#pragma unroll
    for (int i = 0; i < 4; i++)
      bf2[i] = *(const bf16x8*)(sB2 + (wn2 + i * 16 + lrow) * 32 + kqs);
    __syncthreads();   // reads done -> safe to overwrite sB2

    if (k0 + 32 < HID) {
      gl_lds16(gW2,                     lB2);
      gl_lds16(gW2 + (size_t)128 * 512, lB2 + 4096);
      gW2 += 32;
    }

    __builtin_amdgcn_s_setprio(1);
#pragma unroll
    for (int mi = 0; mi < 4; mi++)
#pragma unroll
      for (int ni = 0; ni < 4; ni++)
        acc2[mi][ni] = __builtin_amdgcn_mfma_f32_16x16x32_bf16(af2[mi], bf2[ni], acc2[mi][ni], 0, 0, 0);
    __builtin_amdgcn_s_setprio(0);
    __syncthreads();
  }

  // ---- epilogue: msg -> LDS f32, segment-reduce sorted runs ----
  {
    float* msgL = (float*)smem;      // [128][260] padded
#pragma unroll
    for (int ni = 0; ni < 4; ni++) {
      int gcol = wn2 + ni * 16 + ccol;
      float bv = b2[gcol];
#pragma unroll
      for (int mi = 0; mi < 4; mi++) {
#pragma unroll
        for (int r = 0; r < 4; r++)
          msgL[(wm + mi * 16 + crow + r) * 260 + gcol] = acc2[mi][ni][r] + bv;
      }
    }
    __syncthreads();

    const int c = t & 255;           // column
    const int h = t >> 8;            // row half 0/1 (wave-uniform)
    int r = h * 64;
    const int rend = h * 64 + 64;
    while (r < rend) {
      int id = sDst[r];
      if (r > 0 && sDst[r - 1] == id) { r++; continue; }  // mid-run: owned by earlier head
      float s2 = msgL[r * 260 + c];
      int rr = r + 1;
      while (rr < 128 && sDst[rr] == id) { s2 += msgL[rr * 260 + c]; rr++; }
      if (r == 0 || rr == 128)       // run may continue in neighbor block
        atomicAdd(&sums[(size_t)id * 256 + c], s2);
      else                           // node fully owned by this block
        sums[(size_t)id * 256 + c] = s2;
      r = rr;
    }
  }
}

// ---------------- generic bf16 MFMA GEMM (dbuf pipelined): C = A @ B^T + bias ----------------
template <int ACT, int OMODE, int GRUSEL>
__global__ __launch_bounds__(512) void gemm_bt2(
    const bf16_t* __restrict__ A, const bf16_t* __restrict__ B,
    const float* __restrict__ bias, void* __restrict__ Cout,
    const bf16_t* __restrict__ A2, const float* __restrict__ bias2,
    void* __restrict__ Cout2,
    const int* __restrict__ dstid, float* __restrict__ sums,
    int M, int N, int K) {
  // dbuf: A0@0(4096) B0@4096(8192) A1@12288 B1@16384 -> 24576 elems = 48KB
  __shared__ alignas(16) bf16_t sT[24576];

  int bm = blockIdx.y, bn = blockIdx.x;
  if (GRUSEL && blockIdx.z == 1) { A = A2; bias = bias2; Cout = Cout2; }

  const int t = threadIdx.x;
  const int lane = t & 63;
  const int wave = t >> 6;
  const int wm = (wave >> 2) * 64;
  const int wn = (wave & 3) * 64;

  f32x4 acc[4][4];
#pragma unroll
  for (int i = 0; i < 4; i++)
#pragma unroll
    for (int j = 0; j < 4; j++) acc[i][j] = (f32x4){0.f, 0.f, 0.f, 0.f};

  const int gs8 = (((t & 3) ^ ((t >> 3) & 3))) * 8;
  const bf16_t* gA = A + ((size_t)bm * 128 + (t >> 2)) * K + gs8;
  const bf16_t* gB = B + ((size_t)bn * 256 + (t >> 2)) * K + gs8;
  const size_t gB2off = (size_t)128 * K;

  const int lrow = lane & 15;
  const int kqs  = ((lane >> 4) ^ ((lane >> 1) & 3)) * 8;

  // prologue: stage chunk 0 into buf0
  {
    bf16_t* lA = sT + (size_t)t * 8;
    bf16_t* lB = sT + 4096 + (size_t)t * 8;
    gl_lds16(gA, lA);
    gl_lds16(gB, lB);
    gl_lds16(gB + gB2off, lB + 4096);
    gA += 32; gB += 32;
  }
  __syncthreads();

  int cur = 0;
  const int nk = K >> 5;
  for (int k = 0; k < nk; ++k) {
    const int nxt = cur ^ 1;
    if (k + 1 < nk) {
      bf16_t* lA = sT + (nxt ? 12288 : 0) + (size_t)t * 8;
      bf16_t* lB = sT + (nxt ? 16384 : 4096) + (size_t)t * 8;
      gl_lds16(gA, lA);
      gl_lds16(gB, lB);
      gl_lds16(gB + gB2off, lB + 4096);
      gA += 32; gB += 32;
    }
    const bf16_t* bA = sT + (cur ? 12288 : 0);
    const bf16_t* bB = sT + (cur ? 16384 : 4096);
    bf16x8 af[4], bfr[4];
#pragma unroll
    for (int i = 0; i < 4; i++) af[i]  = *(const bf16x8*)(bA + (wm + i * 16 + lrow) * 32 + kqs);
#pragma unroll
    for (int i = 0; i < 4; i++) bfr[i] = *(const bf16x8*)(bB + (wn + i * 16 + lrow) * 32 + kqs);

    __builtin_amdgcn_s_setprio(1);
#pragma unroll
    for (int mi = 0; mi < 4; mi++)
#pragma unroll
      for (int ni = 0; ni < 4; ni++)
        acc[mi][ni] = __builtin_amdgcn_mfma_f32_16x16x32_bf16(af[mi], bfr[ni], acc[mi][ni], 0, 0, 0);
    __builtin_amdgcn_s_setprio(0);
    __syncthreads();
    cur = nxt;
  }

  const int crow = (lane >> 4) * 4;
  const int ccol = lane & 15;
  if (OMODE == 2) {
#pragma unroll
    for (int mi = 0; mi < 4; mi++) {
      int id4[4];
#pragma unroll
      for (int r = 0; r < 4; r++)
        id4[r] = dstid[(size_t)bm * 128 + wm + mi * 16 + crow + r];
#pragma unroll
      for (int ni = 0; ni < 4; ni++) {
        int gcol = wn + ni * 16 + ccol;
        float bv = bias[gcol];
#pragma unroll
        for (int r = 0; r < 4; r++)
          atomicAdd(&sums[(size_t)id4[r] * 256 + gcol], acc[mi][ni][r] + bv);
      }
    }
  } else {
#pragma unroll
    for (int ni = 0; ni < 4; ni++) {
      int gcol = bn * 256 + wn + ni * 16 + ccol;
      float bv = bias[gcol];
#pragma unroll
      for (int mi = 0; mi < 4; mi++) {
#pragma unroll
        for (int r = 0; r < 4; r++) {
          size_t grow = (size_t)bm * 128 + wm + mi * 16 + crow + r;
          float v = acc[mi][ni][r] + bv;
          if (ACT) v = fmaxf(v, 0.f);
          ((unsigned short*)Cout)[grow * N + gcol] = f2bf(v);
        }
      }
    }
  }
}

// ---------------- unique / sort machinery ----------------
__global__ void mark_k(const int* __restrict__ dst, int* __restrict__ icnt) {
  int e = blockIdx.x * 256 + threadIdx.x;
  if (e < E_EDGES) atomicAdd(&icnt[dst[e]], 1);
}

__global__ void fill_k(float* __restrict__ uo, int* __restrict__ slot_id) {
  int j = blockIdx.x * 256 + threadIdx.x;
  if (j < NN) { uo[j] = (float)NN; slot_id[j] = -1; }
}

// dual scan over icnt: rank = exclusive scan of (icnt>0), offs = exclusive scan of icnt
__global__ void scan2_k(const int* __restrict__ icnt, int* __restrict__ rank,
                        int* __restrict__ offs) {
  __shared__ int pf[1024], pc[1024];
  int t = threadIdx.x;
  int base = t * 32;
  int sf = 0, sc = 0;
  for (int i = 0; i < 32; i++) { int v = icnt[base + i]; sf += (v > 0); sc += v; }
  pf[t] = sf; pc[t] = sc;
  __syncthreads();
  for (int off = 1; off < 1024; off <<= 1) {
    int vf = (t >= off) ? pf[t - off] : 0;
    int vc = (t >= off) ? pc[t - off] : 0;
    __syncthreads();
    pf[t] += vf; pc[t] += vc;
    __syncthreads();
  }
  int runf = (t == 0) ? 0 : pf[t - 1];
  int runc = (t == 0) ? 0 : pc[t - 1];
  for (int i = 0; i < 32; i++) {
    int v = icnt[base + i];
    rank[base + i] = runf; runf += (v > 0);
    offs[base + i] = runc; runc += v;
  }
}

__global__ void scatter_ids(const int* __restrict__ icnt, const int* __restrict__ rank,
                            float* __restrict__ uo, int* __restrict__ slot_id) {
  int id = blockIdx.x * 256 + threadIdx.x;
  if (id < NN && icnt[id] > 0) {
    int s = rank[id];
    uo[s] = (float)id;
    slot_id[s] = id;
  }
}

// counting-sort: perm[pos] = edge index, dsts[pos] = its dst id (sorted)
__global__ void scatter_edges(const int* __restrict__ dst, const int* __restrict__ offs,
                              int* __restrict__ cursor, int* __restrict__ perm,
                              int* __restrict__ dsts) {
  int e = blockIdx.x * 256 + threadIdx.x;
  if (e < E_EDGES) {
    int id = dst[e];
    int pos = offs[id] + atomicAdd(&cursor[id], 1);
    perm[pos] = e;
    dsts[pos] = id;
  }
}

__global__ void agg_pack(const int* __restrict__ slot_id, const float* __restrict__ sums,
                         const int* __restrict__ icnt, const float* __restrict__ dmem,
                         unsigned short* __restrict__ aggb, unsigned short* __restrict__ prevb) {
  int j = blockIdx.x, t = threadIdx.x;
  int id = slot_id[j];
  float a = 0.f;
  if (id >= 0) a = sums[(size_t)id * 256 + t] / fmaxf((float)icnt[id], 1.f);
  aggb[(size_t)j * 256 + t] = f2bf(a);
  prevb[(size_t)j * 256 + t] = f2bf(dmem[(size_t)j * 256 + t]);
}

__global__ void gru_gate(const unsigned short* __restrict__ gi,
                         const unsigned short* __restrict__ gh,
                         const float* __restrict__ dmem, float* __restrict__ out) {
  int j = blockIdx.x, t = threadIdx.x;
  size_t b = (size_t)j * 768;
  auto bf = [](unsigned short u) { return __uint_as_float((unsigned int)u << 16); };
  float gir = bf(gi[b + t]), giz = bf(gi[b + 256 + t]), gin = bf(gi[b + 512 + t]);
  float ghr = bf(gh[b + t]), ghz = bf(gh[b + 256 + t]), ghn = bf(gh[b + 512 + t]);
  float r = 1.f / (1.f + expf(-(gir + ghr)));
  float z = 1.f / (1.f + expf(-(giz + ghz)));
  float n = tanhf(gin + r * ghn);
  float prev = dmem[(size_t)j * 256 + t];
  out[(size_t)NN + (size_t)j * 256 + t] = (1.f - z) * n + z * prev;
}

extern "C" void kernel_launch(void* const* d_in, const int* in_sizes, int n_in,
                              void* d_out, int out_size, void* d_ws, size_t ws_size,
                              hipStream_t stream) {
  const float* rel  = (const float*)d_in[0];
  const float* src  = (const float*)d_in[1];
  const float* dmem = (const float*)d_in[2];
  const float* edge = (const float*)d_in[3];
  const int*   dst  = (const int*)d_in[4];
  const float* tw   = (const float*)d_in[5];
  const float* tb   = (const float*)d_in[6];
  const float* w1   = (const float*)d_in[7];
  const float* b1   = (const float*)d_in[8];
  const float* w2   = (const float*)d_in[9];
  const float* b2   = (const float*)d_in[10];
  const float* wih  = (const float*)d_in[11];
  const float* whh  = (const float*)d_in[12];
  const float* bih  = (const float*)d_in[13];
  const float* bhh  = (const float*)d_in[14];

  char* ws = (char*)d_ws;
  size_t o = 0;
  auto take = [&](size_t bytes) -> char* {
    char* p = ws + o;
    o += (bytes + 255) & ~(size_t)255;
    return p;
  };

  unsigned short* gib   = (unsigned short*)take((size_t)NN * 768 * 2);
  unsigned short* ghb   = (unsigned short*)take((size_t)NN * 768 * 2);
  float* sums           = (float*)take((size_t)NN * 256 * 4);
  int*   icnt           = (int*)take((size_t)NN * 4);
  int*   rank           = (int*)take((size_t)NN * 4);
  int*   offs           = (int*)take((size_t)NN * 4);
  int*   cursor         = (int*)take((size_t)NN * 4);
  int*   slot_id        = (int*)take((size_t)NN * 4);
  int*   perm           = (int*)take((size_t)E_EDGES * 4);
  int*   dsts           = (int*)take((size_t)E_EDGES * 4);
  unsigned short* aggb  = (unsigned short*)take((size_t)NN * 256 * 2);
  unsigned short* prevb = (unsigned short*)take((size_t)NN * 256 * 2);
  unsigned short* w1b   = (unsigned short*)take((size_t)HID * INDIM * 2);
  unsigned short* w2b   = (unsigned short*)take((size_t)MSGD * HID * 2);
  unsigned short* wihb  = (unsigned short*)take((size_t)768 * 256 * 2);
  unsigned short* whhb  = (unsigned short*)take((size_t)768 * 256 * 2);

  float* outf = (float*)d_out;

  hipMemsetAsync(sums, 0, (size_t)NN * 256 * 4, stream);
  hipMemsetAsync(icnt, 0, (size_t)NN * 4, stream);
  hipMemsetAsync(cursor, 0, (size_t)NN * 4, stream);

  int n1 = HID * INDIM;
  int n2 = MSGD * HID;
  int n3 = 768 * 256;
  cvt_bf16<<<(n1 + 255) / 256, 256, 0, stream>>>(w1, w1b, n1);
  cvt_bf16<<<(n2 + 255) / 256, 256, 0, stream>>>(w2, w2b, n2);
  cvt_bf16<<<(n3 + 255) / 256, 256, 0, stream>>>(wih, wihb, n3);
  cvt_bf16<<<(n3 + 255) / 256, 256, 0, stream>>>(whh, whhb, n3);

  mark_k<<<E_EDGES / 256, 256, 0, stream>>>(dst, icnt);
  scan2_k<<<1, 1024, 0, stream>>>(icnt, rank, offs);
  scatter_edges<<<E_EDGES / 256, 256, 0, stream>>>(dst, offs, cursor, perm, dsts);

  fill_k<<<NN / 256, 256, 0, stream>>>(outf, slot_id);
  scatter_ids<<<NN / 256, 256, 0, stream>>>(icnt, rank, outf, slot_id);

  // fused: h = relu(X@w1^T+b1) in LDS; msg = h@w2^T+b2 segment-reduced into sums
  gemm12_fused<<<dim3(E_EDGES / 128), 512, 0, stream>>>(
      src, dmem, edge, rel, tw, tb, (const bf16_t*)w1b, b1,
      (const bf16_t*)w2b, b2, perm, dsts, sums);

  agg_pack<<<NN, 256, 0, stream>>>(slot_id, sums, icnt, dmem, aggb, prevb);

  // gi = agg @ w_ih^T + b_ih ; gh = prev @ w_hh^T + b_hh  (bf16 out)
  gemm_bt2<0, 1, 1><<<dim3(768 / 256, NN / 128, 2), 512, 0, stream>>>(
      (const bf16_t*)aggb, (const bf16_t*)wihb, bih, gib,
      (const bf16_t*)prevb, bhh, ghb, nullptr, nullptr, NN, 768, 256);

  gru_gate<<<NN, 256, 0, stream>>>(gib, ghb, dmem, outf);
}